// Round 5
// baseline (305.430 us; speedup 1.0000x reference)
//
#include <hip/hip_runtime.h>
#include <cstdint>
#include <cstddef>

#define N 8192
#define F 64
#define NEMB 128
#define BI 16
#define BJ 256
#define NCHUNK (N/BJ)   // 32
#define NBLK (N/BI)     // 512
#define LEAKY 0.01f

typedef __attribute__((ext_vector_type(8))) short bf16x8;
typedef __attribute__((ext_vector_type(4))) float f32x4;

__device__ __forceinline__ float wave_reduce_sum_f(float v){
  #pragma unroll
  for (int d = 32; d > 0; d >>= 1) v += __shfl_xor(v, d, 64);
  return v;
}
__device__ __forceinline__ int wave_reduce_sum_i(int v){
  #pragma unroll
  for (int d = 32; d > 0; d >>= 1) v += __shfl_xor(v, d, 64);
  return v;
}
__device__ __forceinline__ unsigned short f2bf(float x){
  union { float f; unsigned u; } v; v.f = x;
  unsigned r = v.u + 0x7fff + ((v.u >> 16) & 1);
  return (unsigned short)(r >> 16);
}

// Kernel A: h = x @ W^T + b; ssrc; sdst duplicated x2; block 0 zeroes lookback state
extern "C" __global__ void __launch_bounds__(256)
k_h(const float* __restrict__ x, const float* __restrict__ ww, const float* __restrict__ wb,
    const float* __restrict__ aw, float* __restrict__ h,
    float* __restrict__ ssrc, float* __restrict__ sdst2x,
    unsigned* __restrict__ partials, int* __restrict__ ticket){
  const int t = threadIdx.x, w = t >> 6, lane = t & 63;
  if (blockIdx.x == 0){
    partials[t] = 0; partials[t + 256] = 0;
    if (t == 0) *ticket = 0;
  }
  __shared__ float xs[4][NEMB];
  const int n0 = blockIdx.x * 4;
  ((float2*)&xs[0][0])[t] = ((const float2*)(x + (size_t)n0 * NEMB))[t];
  __syncthreads();
  const int n = n0 + w;
  const float4* w4 = (const float4*)(ww + (size_t)lane * NEMB);
  const float4* x4 = (const float4*)&xs[w][0];
  float acc = wb[lane];
  #pragma unroll
  for (int k = 0; k < NEMB/4; ++k){
    float4 a = x4[k]; float4 b = w4[k];
    acc = fmaf(a.x, b.x, acc);
    acc = fmaf(a.y, b.y, acc);
    acc = fmaf(a.z, b.z, acc);
    acc = fmaf(a.w, b.w, acc);
  }
  h[(size_t)n * F + lane] = acc;
  float vs = wave_reduce_sum_f(acc * aw[lane]);
  float vd = wave_reduce_sum_f(acc * aw[F + lane]);
  if (lane == 0){ ssrc[n] = vs; sdst2x[n] = vd; sdst2x[n + N] = vd; }
}

// Kernel A2: transpose h (fp32 [N][F]) -> ht (bf16 [F][N])
extern "C" __global__ void __launch_bounds__(256)
k_tr(const float* __restrict__ h, unsigned short* __restrict__ ht){
  __shared__ float tile[64][65];
  const int t = threadIdx.x;
  const int n0 = blockIdx.x * 64;
  #pragma unroll
  for (int s = 0; s < 4; ++s){
    const int r = s*16 + (t>>4);
    const int c = (t&15)*4;
    const float4 v = *(const float4*)(h + (size_t)(n0+r)*F + c);
    tile[r][c] = v.x; tile[r][c+1] = v.y; tile[r][c+2] = v.z; tile[r][c+3] = v.w;
  }
  __syncthreads();
  const int f = t >> 2, jq = t & 3;
  unsigned short buf[16];
  #pragma unroll
  for (int k = 0; k < 16; ++k) buf[k] = f2bf(tile[jq*16 + k][f]);
  *(uint4*)(ht + (size_t)f*N + n0 + jq*16)     = *(uint4*)&buf[0];
  *(uint4*)(ht + (size_t)f*N + n0 + jq*16 + 8) = *(uint4*)&buf[8];
}

// Fused: adj->bm2 (conflict-free layout) -> lookback -> per-chunk:
//   scan -> direct-global sdst/ssrc gather -> exp -> bf16 p -> pt (dbuf, 1 barrier)
//   -> MFMA with B-fragments direct from global ht
extern "C" __global__ void __launch_bounds__(256, 4)
k_main(const int* __restrict__ adj, const unsigned short* __restrict__ ht,
       const float* __restrict__ ssrc, const float* __restrict__ sdst2x,
       const float* __restrict__ abias,
       unsigned* __restrict__ partials, int* __restrict__ ticket,
       float* __restrict__ out){
  __shared__ __attribute__((aligned(16))) char ptA[16*512];   // 8 KB swizzled
  __shared__ __attribute__((aligned(16))) char ptB[16*512];   // 8 KB swizzled
  __shared__ unsigned short bm2[256][34];                     // 17.4 KB [thread][chunk]
  __shared__ float denom_lds[BI];
  __shared__ int cnt_lds[BI];
  __shared__ int base_lds[BI];
  __shared__ int vid_s, gbase_s;

  const int t = threadIdx.x, w = t >> 6, lane = t & 63;
  if (t == 0) vid_s = atomicAdd(ticket, 1);
  __syncthreads();
  const int vid = vid_s;
  const int i0 = vid * BI;

  // ---- phase 1: read 16 adj rows once, pack words into bm2[thread][chunk] ----
  #pragma unroll
  for (int rr = 0; rr < 4; ++rr){
    const int i = i0 + w*4 + rr;
    const int4* row4 = (const int4*)(adj + (size_t)i * N);
    int rcnt = 0;
    #pragma unroll 8
    for (int it = 0; it < 32; ++it){
      const int4 a = row4[it*64 + lane];
      unsigned nib = (unsigned)(a.x>0) | ((unsigned)(a.y>0)<<1) |
                     ((unsigned)(a.z>0)<<2) | ((unsigned)(a.w>0)<<3);
      rcnt += __popc(nib);
      unsigned word = nib << ((lane & 3) * 4);
      word |= __shfl_xor(word, 1, 64);
      word |= __shfl_xor(word, 2, 64);
      // word (row w*4+rr, word-index it*16+(lane>>2)) -> consumer thread
      if ((lane & 3) == 0) bm2[(w*4+rr)*16 + (lane>>2)][it] = (unsigned short)word;
    }
    rcnt = wave_reduce_sum_i(rcnt);
    if (lane == 0) cnt_lds[w*4+rr] = rcnt;
  }
  __syncthreads();

  // ---- block scan + 64-wide parallel lookback (wave 0) ----
  if (w == 0){
    int tot = 0;
    if (lane == 0){
      int run = 0;
      #pragma unroll
      for (int k = 0; k < BI; ++k){ int c = cnt_lds[k]; base_lds[k] = run; run += c; }
      tot = run;
      const unsigned pub = ((unsigned)run << 2) | (vid == 0 ? 2u : 1u);
      __hip_atomic_store(&partials[vid], pub, __ATOMIC_RELEASE, __HIP_MEMORY_SCOPE_AGENT);
    }
    unsigned excl = 0;
    if (vid > 0){
      int look = vid - 1;
      while (true){
        const int idx = look - lane;
        unsigned v = 2u;                  // sentinel past block 0: inclusive 0
        if (idx >= 0){
          do {
            v = __hip_atomic_load(&partials[idx], __ATOMIC_ACQUIRE, __HIP_MEMORY_SCOPE_AGENT);
          } while ((v & 3u) == 0u);
        }
        const unsigned long long ball = __ballot((v & 3u) == 2u);
        if (ball){
          const int L = __ffsll((unsigned long long)ball) - 1;
          excl += (unsigned)wave_reduce_sum_i((lane <= L) ? (int)(v >> 2) : 0);
          break;
        }
        excl += (unsigned)wave_reduce_sum_i((int)(v >> 2));
        look -= 64;
      }
      if (lane == 0)
        __hip_atomic_store(&partials[vid], ((excl + (unsigned)tot) << 2) | 2u,
                           __ATOMIC_RELEASE, __HIP_MEMORY_SCOPE_AGENT);
    }
    if (lane == 0) gbase_s = (int)excl;
  }
  __syncthreads();

  const int r = t >> 4, g = t & 15;
  const int fr = lane & 15, ks = lane >> 4;
  const int fB = w*16 + fr;
  const int sA = (fr & 7) << 4;
  const int sw = (r & 7) << 4;
  char* pbA = ptA + r*512;
  char* pbB = ptB + r*512;
  const char* aA = ptA + fr*512;
  const char* aB = ptB + fr*512;
  const float ab = abias[0];
  int rank = gbase_s + base_lds[r];
  float dsum = 0.f;
  f32x4 acc = {0.f, 0.f, 0.f, 0.f};

#define PRODUCE(CH, PB) { \
    const int ch = (CH); \
    const unsigned m = bm2[t][ch]; \
    const int c = __popc(m); \
    int inc = c; \
    _Pragma("unroll") \
    for (int d = 1; d < 16; d <<= 1){ int u = __shfl_up(inc, d, 16); if (g >= d) inc += u; } \
    const int rowtot = __shfl(inc, 15, 16); \
    const int qex = inc - c; \
    const int q0row = rank; rank += rowtot; \
    const float* sdw = sdst2x + (q0row & (N-1)) + qex; \
    const int ilo = q0row >> 13; \
    const float s_lo = ssrc[ilo]; \
    const float s_hi = ssrc[(q0row + (rowtot > 0 ? rowtot - 1 : 0)) >> 13]; \
    const int krel = ((ilo + 1) << 13) - q0row - qex; \
    unsigned pk[8]; \
    _Pragma("unroll") \
    for (int bb = 0; bb < 16; ++bb){ \
      float p = 0.f; \
      if ((m >> bb) & 1u){ \
        const int k = __popc(m & ((1u << bb) - 1u)); \
        const float sd = sdw[k]; \
        const float ss = (k >= krel) ? s_hi : s_lo; \
        float e = ss + sd + ab; \
        e = (e > 0.f) ? e : LEAKY * e; \
        p = __expf(e); \
        dsum += p; \
      } \
      if (bb & 1) pk[bb >> 1] |= (unsigned)f2bf(p) << 16; \
      else        pk[bb >> 1]  = (unsigned)f2bf(p); \
    } \
    *(uint4*)(PB + ((g*32)      ^ sw)) = make_uint4(pk[0], pk[1], pk[2], pk[3]); \
    *(uint4*)(PB + ((g*32 + 16) ^ sw)) = make_uint4(pk[4], pk[5], pk[6], pk[7]); \
  }

#define MM(CH, AP) { \
    const unsigned short* hB = ht + (size_t)fB*N + (CH)*BJ + ks*8; \
    __syncthreads(); \
    _Pragma("unroll") \
    for (int kk = 0; kk < 8; ++kk){ \
      bf16x8 av = *(const bf16x8*)((AP) + ((kk*64 + ks*16) ^ sA)); \
      bf16x8 bv = *(const bf16x8*)(hB + kk*32); \
      acc = __builtin_amdgcn_mfma_f32_16x16x32_bf16(av, bv, acc, 0, 0, 0); \
    } \
  }

  for (int cc = 0; cc < NCHUNK; cc += 2){
    PRODUCE(cc,     pbA)
    MM(cc, aA)
    PRODUCE(cc + 1, pbB)
    MM(cc + 1, aB)
  }
#undef PRODUCE
#undef MM

  // ---- denominators: reduce dsum within each 16-lane row group ----
  #pragma unroll
  for (int d = 8; d > 0; d >>= 1) dsum += __shfl_xor(dsum, d, 16);
  if (g == 0) denom_lds[r] = dsum;
  __syncthreads();
  // ---- epilogue: C/D layout col=lane&15, row=(lane>>4)*4+reg ----
  #pragma unroll
  for (int reg = 0; reg < 4; ++reg){
    const int il = ks*4 + reg;
    const float dn = denom_lds[il];
    float v = (dn > 0.f) ? acc[reg] / dn : 0.f;
    const float o = (v > 0.f) ? v : (__expf(v) - 1.f);
    out[(size_t)(i0 + il)*F + w*16 + fr] = o;
  }
}

extern "C" void kernel_launch(void* const* d_in, const int* in_sizes, int n_in,
                              void* d_out, int out_size, void* d_ws, size_t ws_size,
                              hipStream_t stream){
  const float* x   = (const float*)d_in[0];
  const int*   adj = (const int*)d_in[1];
  const float* ww  = (const float*)d_in[2];
  const float* wb  = (const float*)d_in[3];
  const float* aw  = (const float*)d_in[4];
  const float* ab  = (const float*)d_in[5];
  float* out = (float*)d_out;

  char* ws = (char*)d_ws;
  float*          h        = (float*)(ws);                                  // 2 MB
  unsigned short* ht       = (unsigned short*)(ws + (size_t)N*F*4);         // 1 MB
  float*          ssrc     = (float*)(ws + (size_t)N*F*4 + (size_t)N*F*2);  // 32 KB
  float*          sdst2x   = ssrc + N;                                      // 64 KB
  unsigned*       partials = (unsigned*)(sdst2x + 2*N);                     // 2 KB
  int*            ticket   = (int*)(partials + NBLK);                       // 4 B

  k_h   <<<N/4,  256, 0, stream>>>(x, ww, wb, aw, h, ssrc, sdst2x, partials, ticket);
  k_tr  <<<N/64, 256, 0, stream>>>(h, ht);
  k_main<<<NBLK, 256, 0, stream>>>(adj, ht, ssrc, sdst2x, ab, partials, ticket, out);
}

// Round 7
// 245.199 us; speedup vs baseline: 1.2456x; 1.2456x over previous
//
#include <hip/hip_runtime.h>
#include <cstdint>
#include <cstddef>

#define N 8192
#define F 64
#define NEMB 128
#define BI 16
#define BJ 256
#define NCHUNK (N/BJ)   // 32
#define NBLK (N/BI)     // 512
#define LEAKY 0.01f

typedef __attribute__((ext_vector_type(8))) short bf16x8;
typedef __attribute__((ext_vector_type(4))) float f32x4;

__device__ __forceinline__ float wave_reduce_sum_f(float v){
  #pragma unroll
  for (int d = 32; d > 0; d >>= 1) v += __shfl_xor(v, d, 64);
  return v;
}
__device__ __forceinline__ int wave_reduce_sum_i(int v){
  #pragma unroll
  for (int d = 32; d > 0; d >>= 1) v += __shfl_xor(v, d, 64);
  return v;
}
__device__ __forceinline__ unsigned short f2bf(float x){
  union { float f; unsigned u; } v; v.f = x;
  unsigned r = v.u + 0x7fff + ((v.u >> 16) & 1);
  return (unsigned short)(r >> 16);
}

// Kernel A: h = x @ W^T + b; ssrc; sdst duplicated x2; block 0 zeroes lookback state
extern "C" __global__ void __launch_bounds__(256)
k_h(const float* __restrict__ x, const float* __restrict__ ww, const float* __restrict__ wb,
    const float* __restrict__ aw, float* __restrict__ h,
    float* __restrict__ ssrc, float* __restrict__ sdst2x,
    unsigned* __restrict__ partials, int* __restrict__ ticket){
  const int t = threadIdx.x, w = t >> 6, lane = t & 63;
  if (blockIdx.x == 0){
    partials[t] = 0; partials[t + 256] = 0;
    if (t == 0) *ticket = 0;
  }
  __shared__ float xs[4][NEMB];
  const int n0 = blockIdx.x * 4;
  ((float2*)&xs[0][0])[t] = ((const float2*)(x + (size_t)n0 * NEMB))[t];
  __syncthreads();
  const int n = n0 + w;
  const float4* w4 = (const float4*)(ww + (size_t)lane * NEMB);
  const float4* x4 = (const float4*)&xs[w][0];
  float acc = wb[lane];
  #pragma unroll
  for (int k = 0; k < NEMB/4; ++k){
    float4 a = x4[k]; float4 b = w4[k];
    acc = fmaf(a.x, b.x, acc);
    acc = fmaf(a.y, b.y, acc);
    acc = fmaf(a.z, b.z, acc);
    acc = fmaf(a.w, b.w, acc);
  }
  h[(size_t)n * F + lane] = acc;
  float vs = wave_reduce_sum_f(acc * aw[lane]);
  float vd = wave_reduce_sum_f(acc * aw[F + lane]);
  if (lane == 0){ ssrc[n] = vs; sdst2x[n] = vd; sdst2x[n + N] = vd; }
}

// Kernel A2: transpose h (fp32 [N][F]) -> ht (bf16 [F][N])
extern "C" __global__ void __launch_bounds__(256)
k_tr(const float* __restrict__ h, unsigned short* __restrict__ ht){
  __shared__ float tile[64][65];
  const int t = threadIdx.x;
  const int n0 = blockIdx.x * 64;
  #pragma unroll
  for (int s = 0; s < 4; ++s){
    const int r = s*16 + (t>>4);
    const int c = (t&15)*4;
    const float4 v = *(const float4*)(h + (size_t)(n0+r)*F + c);
    tile[r][c] = v.x; tile[r][c+1] = v.y; tile[r][c+2] = v.z; tile[r][c+3] = v.w;
  }
  __syncthreads();
  const int f = t >> 2, jq = t & 3;
  unsigned short buf[16];
  #pragma unroll
  for (int k = 0; k < 16; ++k) buf[k] = f2bf(tile[jq*16 + k][f]);
  *(uint4*)(ht + (size_t)f*N + n0 + jq*16)     = *(uint4*)&buf[0];
  *(uint4*)(ht + (size_t)f*N + n0 + jq*16 + 8) = *(uint4*)&buf[8];
}

// Fused, 512 threads (8 waves): adj->word masks -> ccum per-chunk rank table ->
// lookback -> two wave-groups each handle 16 chunks (R5-proven produce + MFMA with
// register B-prefetch) -> combine partial acc/denominators -> elu -> out.
extern "C" __global__ void __launch_bounds__(512, 4)
k_main(const int* __restrict__ adj, const unsigned short* __restrict__ ht,
       const float* __restrict__ ssrc, const float* __restrict__ sdst2x,
       const float* __restrict__ abias,
       unsigned* __restrict__ partials, int* __restrict__ ticket,
       float* __restrict__ out){
  __shared__ __attribute__((aligned(16))) char ptA[16*512];   // 8 KB group-0 A-tile
  __shared__ __attribute__((aligned(16))) char ptB[16*512];   // 8 KB group-1 A-tile
  __shared__ unsigned short bm[BI][530];                      // ~17 KB word masks
  __shared__ unsigned short ccum[BI][NCHUNK + 2];             // per-chunk excl ranks
  __shared__ float accf[BI][F];                               // 4 KB combine buffer
  __shared__ float denom2[2][BI];
  __shared__ int basel[BI];
  __shared__ int vid_s, gbase_s;

  const int t = threadIdx.x, w = t >> 6, lane = t & 63;
  if (t == 0) vid_s = atomicAdd(ticket, 1);
  __syncthreads();
  const int vid = vid_s;
  const int i0 = vid * BI;

  // ---- phase 1: read 16 adj rows once (2 per wave), pack 16-bit words ----
  #pragma unroll
  for (int rr = 0; rr < 2; ++rr){
    const int i = i0 + w*2 + rr;
    const int4* row4 = (const int4*)(adj + (size_t)i * N);
    #pragma unroll 8
    for (int it = 0; it < 32; ++it){
      const int4 a = row4[it*64 + lane];
      unsigned nib = (unsigned)(a.x>0) | ((unsigned)(a.y>0)<<1) |
                     ((unsigned)(a.z>0)<<2) | ((unsigned)(a.w>0)<<3);
      unsigned word = nib << ((lane & 3) * 4);
      word |= __shfl_xor(word, 1, 64);
      word |= __shfl_xor(word, 2, 64);
      if ((lane & 3) == 0) bm[w*2+rr][it*16 + (lane>>2)] = (unsigned short)word;
    }
  }
  __syncthreads();

  // ---- phase 1b: per-chunk popcounts (512 threads = 16 rows x 32 chunks) ----
  {
    const int rr2 = t >> 5, cc2 = t & 31;
    int s = 0;
    #pragma unroll
    for (int jj = 0; jj < 8; ++jj)
      s += __popc(*(const unsigned*)&bm[rr2][cc2*16 + jj*2]);
    ccum[rr2][cc2] = (unsigned short)s;
  }
  __syncthreads();

  // ---- phase 1c: in-place exclusive scans + 64-wide parallel lookback (wave 0) ----
  if (w == 0){
    if (lane < BI){
      int run = 0;
      #pragma unroll
      for (int c = 0; c < NCHUNK; ++c){
        int v = ccum[lane][c]; ccum[lane][c] = (unsigned short)run; run += v;
      }
      ccum[lane][NCHUNK] = (unsigned short)run;
    }
    int tot = 0;
    if (lane == 0){
      int run = 0;
      #pragma unroll
      for (int k = 0; k < BI; ++k){ int c = ccum[k][NCHUNK]; basel[k] = run; run += c; }
      tot = run;
      const unsigned pub = ((unsigned)run << 2) | (vid == 0 ? 2u : 1u);
      __hip_atomic_store(&partials[vid], pub, __ATOMIC_RELEASE, __HIP_MEMORY_SCOPE_AGENT);
    }
    unsigned excl = 0;
    if (vid > 0){
      int look = vid - 1;
      while (true){
        const int idx = look - lane;
        unsigned v = 2u;                  // sentinel past block 0: inclusive 0
        if (idx >= 0){
          do {
            v = __hip_atomic_load(&partials[idx], __ATOMIC_ACQUIRE, __HIP_MEMORY_SCOPE_AGENT);
          } while ((v & 3u) == 0u);
        }
        const unsigned long long ball = __ballot((v & 3u) == 2u);
        if (ball){
          const int L = __ffsll((unsigned long long)ball) - 1;
          excl += (unsigned)wave_reduce_sum_i((lane <= L) ? (int)(v >> 2) : 0);
          break;
        }
        excl += (unsigned)wave_reduce_sum_i((int)(v >> 2));
        look -= 64;
      }
      if (lane == 0)
        __hip_atomic_store(&partials[vid], ((excl + (unsigned)tot) << 2) | 2u,
                           __ATOMIC_RELEASE, __HIP_MEMORY_SCOPE_AGENT);
    }
    if (lane == 0) gbase_s = (int)excl;
  }
  __syncthreads();

  // ---- chunk loop: group gg = w>>2 handles chunks [gg*16, gg*16+16) ----
  const int gg = w >> 2, wl = w & 3, tt = t & 255;
  const int r = tt >> 4, g = tt & 15;       // produce roles (R5-proven 16-wide)
  const int fr = lane & 15, ks = lane >> 4; // mfma fragment roles
  const int fB = wl*16 + fr;
  char* PT = gg ? ptB : ptA;
  char* pb = PT + r*512;
  const char* aP = PT + fr*512;
  const int sA = (fr & 7) << 4;
  const int sw = (r & 7) << 4;
  const float ab = abias[0];
  const int rowbase = gbase_s + basel[r];
  const int ch0 = gg * 16;
  float dsum = 0.f;
  f32x4 acc = {0.f, 0.f, 0.f, 0.f};
  bf16x8 breg[8];

#define PREFETCH(CH) { \
    const unsigned short* hBp = ht + (size_t)fB*N + (CH)*BJ + ks*8; \
    _Pragma("unroll") \
    for (int kk = 0; kk < 8; ++kk) breg[kk] = *(const bf16x8*)(hBp + kk*32); \
  }

  PREFETCH(ch0)
  for (int cc = 0; cc < 16; ++cc){
    const int ch = ch0 + cc;
    // ---- produce p for chunk ch (R5-proven body, rank from ccum table) ----
    {
      const unsigned m = (unsigned)bm[r][ch*16 + g];
      const int c = __popc(m);
      int inc = c;
      #pragma unroll
      for (int d = 1; d < 16; d <<= 1){
        int u = __shfl_up(inc, d, 16);
        if (g >= d) inc += u;
      }
      const int qex = inc - c;
      const int crank = (int)ccum[r][ch];
      const int rowtot = (int)ccum[r][ch+1] - crank;
      const int q0row = rowbase + crank;
      const float* sdw = sdst2x + (q0row & (N - 1)) + qex;
      const int ilo = q0row >> 13;
      const float s_lo = ssrc[ilo];
      const float s_hi = ssrc[(q0row + (rowtot > 0 ? rowtot - 1 : 0)) >> 13];
      const int krel = ((ilo + 1) << 13) - q0row - qex;
      unsigned pk[8];
      #pragma unroll
      for (int bb = 0; bb < 16; ++bb){
        float p = 0.f;
        if ((m >> bb) & 1u){
          const int k = __popc(m & ((1u << bb) - 1u));
          const float sd = sdw[k];
          const float ss = (k >= krel) ? s_hi : s_lo;
          float e = ss + sd + ab;
          e = (e > 0.f) ? e : LEAKY * e;
          p = __expf(e);
          dsum += p;
        }
        if (bb & 1) pk[bb >> 1] |= (unsigned)f2bf(p) << 16;
        else        pk[bb >> 1]  = (unsigned)f2bf(p);
      }
      *(uint4*)(pb + ((g*32)      ^ sw)) = make_uint4(pk[0], pk[1], pk[2], pk[3]);
      *(uint4*)(pb + ((g*32 + 16) ^ sw)) = make_uint4(pk[4], pk[5], pk[6], pk[7]);
    }
    __syncthreads();
    // ---- MFMA: 8 K-steps of 16x16x32, B from prefetched registers ----
    #pragma unroll
    for (int kk = 0; kk < 8; ++kk){
      bf16x8 av = *(const bf16x8*)(aP + ((kk*64 + ks*16) ^ sA));
      acc = __builtin_amdgcn_mfma_f32_16x16x32_bf16(av, breg[kk], acc, 0, 0, 0);
    }
    if (cc + 1 < 16) PREFETCH(ch + 1)
    __syncthreads();
  }
#undef PREFETCH

  // ---- combine: denominators + group-1 partial numerators through LDS ----
  #pragma unroll
  for (int d = 8; d > 0; d >>= 1) dsum += __shfl_xor(dsum, d, 16);
  if (g == 0) denom2[gg][r] = dsum;
  if (gg == 1){
    #pragma unroll
    for (int reg = 0; reg < 4; ++reg){
      const int il = ks*4 + reg;
      accf[il][fB] = acc[reg];
    }
  }
  __syncthreads();
  if (gg == 0){
    #pragma unroll
    for (int reg = 0; reg < 4; ++reg){
      const int il = ks*4 + reg;
      const float dn = denom2[0][il] + denom2[1][il];
      float v = acc[reg] + accf[il][fB];
      v = (dn > 0.f) ? v / dn : 0.f;
      const float o = (v > 0.f) ? v : (__expf(v) - 1.f);
      out[(size_t)(i0 + il)*F + fB] = o;
    }
  }
}

extern "C" void kernel_launch(void* const* d_in, const int* in_sizes, int n_in,
                              void* d_out, int out_size, void* d_ws, size_t ws_size,
                              hipStream_t stream){
  const float* x   = (const float*)d_in[0];
  const int*   adj = (const int*)d_in[1];
  const float* ww  = (const float*)d_in[2];
  const float* wb  = (const float*)d_in[3];
  const float* aw  = (const float*)d_in[4];
  const float* ab  = (const float*)d_in[5];
  float* out = (float*)d_out;

  char* ws = (char*)d_ws;
  float*          h        = (float*)(ws);                                  // 2 MB
  unsigned short* ht       = (unsigned short*)(ws + (size_t)N*F*4);         // 1 MB
  float*          ssrc     = (float*)(ws + (size_t)N*F*4 + (size_t)N*F*2);  // 32 KB
  float*          sdst2x   = ssrc + N;                                      // 64 KB
  unsigned*       partials = (unsigned*)(sdst2x + 2*N);                     // 2 KB
  int*            ticket   = (int*)(partials + NBLK);                       // 4 B

  k_h   <<<N/4,  256, 0, stream>>>(x, ww, wb, aw, h, ssrc, sdst2x, partials, ticket);
  k_tr  <<<N/64, 256, 0, stream>>>(h, ht);
  k_main<<<NBLK, 512, 0, stream>>>(adj, ht, ssrc, sdst2x, ab, partials, ticket, out);
}

// Round 9
// 230.473 us; speedup vs baseline: 1.3252x; 1.0639x over previous
//
#include <hip/hip_runtime.h>
#include <cstdint>
#include <cstddef>

#define N 8192
#define F 64
#define NEMB 128
#define BI 16
#define BJ 256
#define NCHUNK (N/BJ)   // 32
#define NBLK (N/BI)     // 512
#define LEAKY 0.01f

typedef __attribute__((ext_vector_type(8))) short bf16x8;
typedef __attribute__((ext_vector_type(4))) float f32x4;

__device__ __forceinline__ float wave_reduce_sum_f(float v){
  #pragma unroll
  for (int d = 32; d > 0; d >>= 1) v += __shfl_xor(v, d, 64);
  return v;
}
__device__ __forceinline__ int wave_reduce_sum_i(int v){
  #pragma unroll
  for (int d = 32; d > 0; d >>= 1) v += __shfl_xor(v, d, 64);
  return v;
}
__device__ __forceinline__ unsigned short f2bf(float x){
  union { float f; unsigned u; } v; v.f = x;
  unsigned r = v.u + 0x7fff + ((v.u >> 16) & 1);
  return (unsigned short)(r >> 16);
}

// Kernel A: h = x @ W^T + b; ssrc; sdst duplicated x2; block 0 zeroes lookback state
extern "C" __global__ void __launch_bounds__(256)
k_h(const float* __restrict__ x, const float* __restrict__ ww, const float* __restrict__ wb,
    const float* __restrict__ aw, float* __restrict__ h,
    float* __restrict__ ssrc, float* __restrict__ sdst2x,
    unsigned* __restrict__ partials, int* __restrict__ ticket){
  const int t = threadIdx.x, w = t >> 6, lane = t & 63;
  if (blockIdx.x == 0){
    partials[t] = 0; partials[t + 256] = 0;
    if (t == 0) *ticket = 0;
  }
  __shared__ float xs[4][NEMB];
  const int n0 = blockIdx.x * 4;
  ((float2*)&xs[0][0])[t] = ((const float2*)(x + (size_t)n0 * NEMB))[t];
  __syncthreads();
  const int n = n0 + w;
  const float4* w4 = (const float4*)(ww + (size_t)lane * NEMB);
  const float4* x4 = (const float4*)&xs[w][0];
  float acc = wb[lane];
  #pragma unroll
  for (int k = 0; k < NEMB/4; ++k){
    float4 a = x4[k]; float4 b = w4[k];
    acc = fmaf(a.x, b.x, acc);
    acc = fmaf(a.y, b.y, acc);
    acc = fmaf(a.z, b.z, acc);
    acc = fmaf(a.w, b.w, acc);
  }
  h[(size_t)n * F + lane] = acc;
  float vs = wave_reduce_sum_f(acc * aw[lane]);
  float vd = wave_reduce_sum_f(acc * aw[F + lane]);
  if (lane == 0){ ssrc[n] = vs; sdst2x[n] = vd; sdst2x[n + N] = vd; }
}

// Kernel A2: transpose h (fp32 [N][F]) -> ht (bf16 [F][N])
extern "C" __global__ void __launch_bounds__(256)
k_tr(const float* __restrict__ h, unsigned short* __restrict__ ht){
  __shared__ float tile[64][65];
  const int t = threadIdx.x;
  const int n0 = blockIdx.x * 64;
  #pragma unroll
  for (int s = 0; s < 4; ++s){
    const int r = s*16 + (t>>4);
    const int c = (t&15)*4;
    const float4 v = *(const float4*)(h + (size_t)(n0+r)*F + c);
    tile[r][c] = v.x; tile[r][c+1] = v.y; tile[r][c+2] = v.z; tile[r][c+3] = v.w;
  }
  __syncthreads();
  const int f = t >> 2, jq = t & 3;
  unsigned short buf[16];
  #pragma unroll
  for (int k = 0; k < 16; ++k) buf[k] = f2bf(tile[jq*16 + k][f]);
  *(uint4*)(ht + (size_t)f*N + n0 + jq*16)     = *(uint4*)&buf[0];
  *(uint4*)(ht + (size_t)f*N + n0 + jq*16 + 8) = *(uint4*)&buf[8];
}

// Fused, 512 threads: adj->word masks -> ccum -> lookback -> two wave-groups,
// each 16 chunks: branch-free produce (window loads + ffs scatter) | dbuf A-tile,
// 1 barrier/chunk, register-dbuf B-prefetch -> combine -> elu.
extern "C" __global__ void __launch_bounds__(512, 4)
k_main(const int* __restrict__ adj, const unsigned short* __restrict__ ht,
       const float* __restrict__ ssrc, const float* __restrict__ sdst2x,
       const float* __restrict__ abias,
       unsigned* __restrict__ partials, int* __restrict__ ticket,
       float* __restrict__ out){
  __shared__ __attribute__((aligned(16))) char pt[2][2][16*512]; // [group][buf] 32 KB
  __shared__ unsigned short bm[BI][530];                         // ~17 KB word masks
  __shared__ unsigned short ccum[BI][NCHUNK + 2];
  __shared__ float accf[BI][F];
  __shared__ float denom2[2][BI];
  __shared__ int basel[BI];
  __shared__ int vid_s, gbase_s;

  const int t = threadIdx.x, w = t >> 6, lane = t & 63;
  if (t == 0) vid_s = atomicAdd(ticket, 1);
  __syncthreads();
  const int vid = vid_s;
  const int i0 = vid * BI;

  // ---- phase 1: read 16 adj rows once (2 per wave), pack 16-bit words ----
  #pragma unroll
  for (int rr = 0; rr < 2; ++rr){
    const int i = i0 + w*2 + rr;
    const int4* row4 = (const int4*)(adj + (size_t)i * N);
    #pragma unroll 8
    for (int it = 0; it < 32; ++it){
      const int4 a = row4[it*64 + lane];
      unsigned nib = (unsigned)(a.x>0) | ((unsigned)(a.y>0)<<1) |
                     ((unsigned)(a.z>0)<<2) | ((unsigned)(a.w>0)<<3);
      unsigned word = nib << ((lane & 3) * 4);
      word |= __shfl_xor(word, 1, 64);
      word |= __shfl_xor(word, 2, 64);
      if ((lane & 3) == 0) bm[w*2+rr][it*16 + (lane>>2)] = (unsigned short)word;
    }
  }
  __syncthreads();

  // ---- phase 1b: per-chunk popcounts (512 threads = 16 rows x 32 chunks) ----
  {
    const int rr2 = t >> 5, cc2 = t & 31;
    int s = 0;
    #pragma unroll
    for (int jj = 0; jj < 8; ++jj)
      s += __popc(*(const unsigned*)&bm[rr2][cc2*16 + jj*2]);
    ccum[rr2][cc2] = (unsigned short)s;
  }
  __syncthreads();

  // ---- phase 1c: exclusive scans + 64-wide parallel lookback (wave 0) ----
  if (w == 0){
    if (lane < BI){
      int run = 0;
      #pragma unroll
      for (int c = 0; c < NCHUNK; ++c){
        int v = ccum[lane][c]; ccum[lane][c] = (unsigned short)run; run += v;
      }
      ccum[lane][NCHUNK] = (unsigned short)run;
    }
    int tot = 0;
    if (lane == 0){
      int run = 0;
      #pragma unroll
      for (int k = 0; k < BI; ++k){ int c = ccum[k][NCHUNK]; basel[k] = run; run += c; }
      tot = run;
      const unsigned pub = ((unsigned)run << 2) | (vid == 0 ? 2u : 1u);
      __hip_atomic_store(&partials[vid], pub, __ATOMIC_RELEASE, __HIP_MEMORY_SCOPE_AGENT);
    }
    unsigned excl = 0;
    if (vid > 0){
      int look = vid - 1;
      while (true){
        const int idx = look - lane;
        unsigned v = 2u;
        if (idx >= 0){
          do {
            v = __hip_atomic_load(&partials[idx], __ATOMIC_ACQUIRE, __HIP_MEMORY_SCOPE_AGENT);
          } while ((v & 3u) == 0u);
        }
        const unsigned long long ball = __ballot((v & 3u) == 2u);
        if (ball){
          const int L = __ffsll((unsigned long long)ball) - 1;
          excl += (unsigned)wave_reduce_sum_i((lane <= L) ? (int)(v >> 2) : 0);
          break;
        }
        excl += (unsigned)wave_reduce_sum_i((int)(v >> 2));
        look -= 64;
      }
      if (lane == 0)
        __hip_atomic_store(&partials[vid], ((excl + (unsigned)tot) << 2) | 2u,
                           __ATOMIC_RELEASE, __HIP_MEMORY_SCOPE_AGENT);
    }
    if (lane == 0) gbase_s = (int)excl;
  }
  __syncthreads();

  // ---- chunk loop: group gg = w>>2 handles chunks [gg*16, gg*16+16) ----
  const int gg = w >> 2, wl = w & 3, tt = t & 255;
  const int r = tt >> 4, g = tt & 15;       // produce roles
  const int fr = lane & 15, ks = lane >> 4; // mfma fragment roles
  const int fB = wl*16 + fr;
  char* buf0 = pt[gg][0];
  char* buf1 = pt[gg][1];
  const int sA = (fr & 7) << 4;
  const int sw = (r & 7) << 4;
  const float ab = abias[0];
  const int rowbase = gbase_s + basel[r];
  const int ch0 = gg * 16;
  float dsum = 0.f;
  f32x4 acc = {0.f, 0.f, 0.f, 0.f};
  bf16x8 bregA[8], bregB[8];

#define PREFETCH(CH, BR) { \
    const unsigned short* hBp = ht + (size_t)fB*N + (CH)*BJ + ks*8; \
    _Pragma("unroll") \
    for (int kk = 0; kk < 8; ++kk) BR[kk] = *(const bf16x8*)(hBp + kk*32); \
  }

  // branch-free produce: window loads + unconditional exp + ffs scatter
#define PRODUCE(CH, PB) { \
    const int ch = (CH); \
    const unsigned m = (unsigned)bm[r][ch*16 + g]; \
    const int c = __popc(m); \
    int inc = c; \
    _Pragma("unroll") \
    for (int d = 1; d < 16; d <<= 1){ int u = __shfl_up(inc, d, 16); if (g >= d) inc += u; } \
    const int qex = inc - c; \
    const int crank = (int)ccum[r][ch]; \
    const int q0row = rowbase + crank; \
    const float* sdw = sdst2x + (q0row & (N - 1)) + qex; \
    const int ilo = q0row >> 13; \
    const float s_lo = ssrc[ilo]; \
    const float s_hi = ssrc[ilo + 1]; \
    const int krel = ((ilo + 1) << 13) - q0row - qex; \
    char* myreg = (PB) + r*512; \
    *(uint4*)(myreg + ((g*32)      ^ sw)) = make_uint4(0,0,0,0); \
    *(uint4*)(myreg + ((g*32 + 16) ^ sw)) = make_uint4(0,0,0,0); \
    float wv[16]; \
    _Pragma("unroll") \
    for (int k = 0; k < 16; ++k) wv[k] = sdw[k]; \
    unsigned mc = m; \
    _Pragma("unroll") \
    for (int k = 0; k < 16; ++k){ \
      const float ss = (k >= krel) ? s_hi : s_lo; \
      float e = ss + wv[k] + ab; \
      e = (e > 0.f) ? e : LEAKY * e; \
      const float p = __expf(e); \
      const int pos = __ffs(mc) - 1; \
      if (k < c){ \
        dsum += p; \
        *(unsigned short*)(myreg + ((g*32 + pos*2) ^ sw)) = f2bf(p); \
      } \
      mc &= mc - 1; \
    } \
  }

#define MM(PB, BR) { \
    const char* aP = (PB) + fr*512; \
    _Pragma("unroll") \
    for (int kk = 0; kk < 8; ++kk){ \
      bf16x8 av = *(const bf16x8*)(aP + ((kk*64 + ks*16) ^ sA)); \
      acc = __builtin_amdgcn_mfma_f32_16x16x32_bf16(av, BR[kk], acc, 0, 0, 0); \
    } \
  }

  PREFETCH(ch0, bregA)
  PRODUCE(ch0, buf0)
  __syncthreads();
  for (int cc = 0; cc < 16; cc += 2){
    PREFETCH(ch0 + cc + 1, bregB)
    PRODUCE(ch0 + cc + 1, buf1)
    MM(buf0, bregA)
    __syncthreads();
    if (cc + 2 < 16){
      PREFETCH(ch0 + cc + 2, bregA)
      PRODUCE(ch0 + cc + 2, buf0)
    }
    MM(buf1, bregB)
    __syncthreads();
  }
#undef PREFETCH
#undef PRODUCE
#undef MM

  // ---- combine: denominators + group-1 partial numerators through LDS ----
  #pragma unroll
  for (int d = 8; d > 0; d >>= 1) dsum += __shfl_xor(dsum, d, 16);
  if (g == 0) denom2[gg][r] = dsum;
  if (gg == 1){
    #pragma unroll
    for (int reg = 0; reg < 4; ++reg){
      const int il = ks*4 + reg;
      accf[il][fB] = acc[reg];
    }
  }
  __syncthreads();
  if (gg == 0){
    #pragma unroll
    for (int reg = 0; reg < 4; ++reg){
      const int il = ks*4 + reg;
      const float dn = denom2[0][il] + denom2[1][il];
      float v = acc[reg] + accf[il][fB];
      v = (dn > 0.f) ? v / dn : 0.f;
      const float o = (v > 0.f) ? v : (__expf(v) - 1.f);
      out[(size_t)(i0 + il)*F + fB] = o;
    }
  }
}

extern "C" void kernel_launch(void* const* d_in, const int* in_sizes, int n_in,
                              void* d_out, int out_size, void* d_ws, size_t ws_size,
                              hipStream_t stream){
  const float* x   = (const float*)d_in[0];
  const int*   adj = (const int*)d_in[1];
  const float* ww  = (const float*)d_in[2];
  const float* wb  = (const float*)d_in[3];
  const float* aw  = (const float*)d_in[4];
  const float* ab  = (const float*)d_in[5];
  float* out = (float*)d_out;

  char* ws = (char*)d_ws;
  float*          h        = (float*)(ws);                                  // 2 MB
  unsigned short* ht       = (unsigned short*)(ws + (size_t)N*F*4);         // 1 MB
  float*          ssrc     = (float*)(ws + (size_t)N*F*4 + (size_t)N*F*2);  // 32 KB
  float*          sdst2x   = ssrc + N;                                      // 64 KB
  unsigned*       partials = (unsigned*)(sdst2x + 2*N);                     // 2 KB
  int*            ticket   = (int*)(partials + NBLK);                       // 4 B

  k_h   <<<N/4,  256, 0, stream>>>(x, ww, wb, aw, h, ssrc, sdst2x, partials, ticket);
  k_tr  <<<N/64, 256, 0, stream>>>(h, ht);
  k_main<<<NBLK, 512, 0, stream>>>(adj, ht, ssrc, sdst2x, ab, partials, ticket, out);
}

// Round 10
// 169.336 us; speedup vs baseline: 1.8037x; 1.3610x over previous
//
#include <hip/hip_runtime.h>
#include <cstdint>
#include <cstddef>

#define N 8192
#define F 64
#define NEMB 128
#define BI 16
#define BJ 256
#define NCHUNK 32
#define HALFCH 16
#define LEAKY 0.01f

typedef __attribute__((ext_vector_type(8))) short bf16x8;
typedef __attribute__((ext_vector_type(4))) float f32x4;

__device__ __forceinline__ float wave_reduce_sum_f(float v){
  #pragma unroll
  for (int d = 32; d > 0; d >>= 1) v += __shfl_xor(v, d, 64);
  return v;
}
__device__ __forceinline__ int wave_reduce_sum_i(int v){
  #pragma unroll
  for (int d = 32; d > 0; d >>= 1) v += __shfl_xor(v, d, 64);
  return v;
}
__device__ __forceinline__ int wave_incl_scan_i(int v, int lane){
  #pragma unroll
  for (int d = 1; d < 64; d <<= 1){
    int u = __shfl_up(v, d, 64);
    if (lane >= d) v += u;
  }
  return v;
}
__device__ __forceinline__ unsigned short f2bf(float x){
  union { float f; unsigned u; } v; v.f = x;
  unsigned r = v.u + 0x7fff + ((v.u >> 16) & 1);
  return (unsigned short)(r >> 16);
}

// Kernel A: h = x @ W^T + b; ssrc; sdst duplicated x2
extern "C" __global__ void __launch_bounds__(256)
k_h(const float* __restrict__ x, const float* __restrict__ ww, const float* __restrict__ wb,
    const float* __restrict__ aw, float* __restrict__ h,
    float* __restrict__ ssrc, float* __restrict__ sdst2x){
  const int t = threadIdx.x, w = t >> 6, lane = t & 63;
  __shared__ float xs[4][NEMB];
  const int n0 = blockIdx.x * 4;
  ((float2*)&xs[0][0])[t] = ((const float2*)(x + (size_t)n0 * NEMB))[t];
  __syncthreads();
  const int n = n0 + w;
  const float4* w4 = (const float4*)(ww + (size_t)lane * NEMB);
  const float4* x4 = (const float4*)&xs[w][0];
  float acc = wb[lane];
  #pragma unroll
  for (int k = 0; k < NEMB/4; ++k){
    float4 a = x4[k]; float4 b = w4[k];
    acc = fmaf(a.x, b.x, acc);
    acc = fmaf(a.y, b.y, acc);
    acc = fmaf(a.z, b.z, acc);
    acc = fmaf(a.w, b.w, acc);
  }
  h[(size_t)n * F + lane] = acc;
  float vs = wave_reduce_sum_f(acc * aw[lane]);
  float vd = wave_reduce_sum_f(acc * aw[F + lane]);
  if (lane == 0){ ssrc[n] = vs; sdst2x[n] = vd; sdst2x[n + N] = vd; }
}

// Kernel A2: transpose h (fp32 [N][F]) -> ht (bf16 [F][N])
extern "C" __global__ void __launch_bounds__(256)
k_tr(const float* __restrict__ h, unsigned short* __restrict__ ht){
  __shared__ float tile[64][65];
  const int t = threadIdx.x;
  const int n0 = blockIdx.x * 64;
  #pragma unroll
  for (int s = 0; s < 4; ++s){
    const int r = s*16 + (t>>4);
    const int c = (t&15)*4;
    const float4 v = *(const float4*)(h + (size_t)(n0+r)*F + c);
    tile[r][c] = v.x; tile[r][c+1] = v.y; tile[r][c+2] = v.z; tile[r][c+3] = v.w;
  }
  __syncthreads();
  const int f = t >> 2, jq = t & 3;
  unsigned short buf[16];
  #pragma unroll
  for (int k = 0; k < 16; ++k) buf[k] = f2bf(tile[jq*16 + k][f]);
  *(uint4*)(ht + (size_t)f*N + n0 + jq*16)     = *(uint4*)&buf[0];
  *(uint4*)(ht + (size_t)f*N + n0 + jq*16 + 8) = *(uint4*)&buf[8];
}

// k_pack: adj row -> chunk-major 16-bit masks + per-row-chunk counts + row total
extern "C" __global__ void __launch_bounds__(256)
k_pack(const int* __restrict__ adj, unsigned short* __restrict__ bm,
       unsigned short* __restrict__ ccnt, int* __restrict__ rowtot){
  const int i = blockIdx.x, t = threadIdx.x;
  int total = 0;
  #pragma unroll
  for (int half = 0; half < 2; ++half){
    const int w = half*256 + t;           // word index 0..511
    const int4* p4 = (const int4*)(adj + (size_t)i*N + w*16);
    unsigned m = 0;
    #pragma unroll
    for (int k = 0; k < 4; ++k){
      int4 a = p4[k];
      m |= (unsigned)(a.x>0) << (k*4+0);
      m |= (unsigned)(a.y>0) << (k*4+1);
      m |= (unsigned)(a.z>0) << (k*4+2);
      m |= (unsigned)(a.w>0) << (k*4+3);
    }
    bm[((size_t)(w>>4)*N + i)*16 + (w&15)] = (unsigned short)m;
    const int pc = __popc(m);
    total += pc;
    int cs = pc;
    cs += __shfl_xor(cs, 1, 16);
    cs += __shfl_xor(cs, 2, 16);
    cs += __shfl_xor(cs, 4, 16);
    cs += __shfl_xor(cs, 8, 16);
    if ((t & 15) == 0) ccnt[(size_t)i*NCHUNK + (w>>4)] = (unsigned short)cs;
  }
  total = wave_reduce_sum_i(total);
  __shared__ int ws_[4];
  if ((t & 63) == 0) ws_[t >> 6] = total;
  __syncthreads();
  if (t == 0) rowtot[i] = ws_[0] + ws_[1] + ws_[2] + ws_[3];
}

// k_scan: exclusive scan of 8192 row totals -> base (R2-proven)
extern "C" __global__ void __launch_bounds__(1024)
k_scan(const int* __restrict__ cnt, int* __restrict__ base){
  __shared__ int wsum[16];
  const int t = threadIdx.x, lane = t & 63, w = t >> 6;
  int4 aa = ((const int4*)cnt)[t * 2];
  int4 bb = ((const int4*)cnt)[t * 2 + 1];
  int v[8] = {aa.x, aa.y, aa.z, aa.w, bb.x, bb.y, bb.z, bb.w};
  int local = 0;
  #pragma unroll
  for (int k = 0; k < 8; ++k){ int tmp = v[k]; v[k] = local; local += tmp; }
  int inc = wave_incl_scan_i(local, lane);
  int wexcl = inc - local;
  if (lane == 63) wsum[w] = inc;
  __syncthreads();
  if (t == 0){
    int run = 0;
    #pragma unroll
    for (int k = 0; k < 16; ++k){ int tmp = wsum[k]; wsum[k] = run; run += tmp; }
  }
  __syncthreads();
  const int b0 = wsum[w] + wexcl;
  ((int4*)base)[t * 2]     = make_int4(b0 + v[0], b0 + v[1], b0 + v[2], b0 + v[3]);
  ((int4*)base)[t * 2 + 1] = make_int4(b0 + v[4], b0 + v[5], b0 + v[6], b0 + v[7]);
}

// k_main: 1024 independent blocks = (vid, half). 256 threads, 16 rows x 16 chunks.
// R9-proven branch-free produce + dbuf A-tile + reg B-prefetch, 1 barrier/chunk.
extern "C" __global__ void __launch_bounds__(256, 4)
k_main(const unsigned short* __restrict__ bm, const unsigned short* __restrict__ ccnt,
       const int* __restrict__ base, const unsigned short* __restrict__ ht,
       const float* __restrict__ ssrc, const float* __restrict__ sdst2x,
       const float* __restrict__ abias,
       float* __restrict__ pnum, float* __restrict__ pden){
  __shared__ __attribute__((aligned(16))) char pt[2][16*512];  // 16 KB dbuf A-tile
  __shared__ unsigned short ccum[BI][HALFCH];                  // chunk start ranks
  __shared__ int basel[BI];

  const int t = threadIdx.x, w = t >> 6, lane = t & 63;
  const int vid = blockIdx.x >> 1, half = blockIdx.x & 1;
  const int i0 = vid * BI;
  const int ch0 = half * HALFCH;

  if (t < BI) basel[t] = base[i0 + t];
  // phase 0: per-row within-row rank offsets for my 16 chunks (from ccnt)
  {
    const int r = t >> 4, g = t & 15;
    int c = (int)ccnt[(size_t)(i0+r)*NCHUNK + ch0 + g];
    int pre = 0;
    if (half){
      pre = (int)ccnt[(size_t)(i0+r)*NCHUNK + g];
      #pragma unroll
      for (int d = 1; d < 16; d <<= 1) pre += __shfl_xor(pre, d, 16);
    }
    int inc = c;
    #pragma unroll
    for (int d = 1; d < 16; d <<= 1){ int u = __shfl_up(inc, d, 16); if (g >= d) inc += u; }
    ccum[r][g] = (unsigned short)(pre + inc - c);
  }
  __syncthreads();

  const int r = t >> 4, g = t & 15;         // produce roles
  const int fr = lane & 15, ks = lane >> 4; // mfma fragment roles
  const int fB = w*16 + fr;
  char* buf0 = pt[0];
  char* buf1 = pt[1];
  const int sA = (fr & 7) << 4;
  const int sw = (r & 7) << 4;
  const float ab = abias[0];
  const int rowbase = basel[r];
  float dsum = 0.f;
  f32x4 acc = {0.f, 0.f, 0.f, 0.f};
  bf16x8 bregA[8], bregB[8];

#define PREFETCH(CH, BR) { \
    const unsigned short* hBp = ht + (size_t)fB*N + (CH)*BJ + ks*8; \
    _Pragma("unroll") \
    for (int kk = 0; kk < 8; ++kk) BR[kk] = *(const bf16x8*)(hBp + kk*32); \
  }

  // branch-free produce: global mask word + window loads + unconditional exp + ffs scatter
#define PRODUCE(CC, PB) { \
    const int cc_ = (CC); \
    const int ch = ch0 + cc_; \
    const unsigned m = (unsigned)bm[((size_t)ch*N + (i0+r))*16 + g]; \
    const int c = __popc(m); \
    int inc = c; \
    _Pragma("unroll") \
    for (int d = 1; d < 16; d <<= 1){ int u = __shfl_up(inc, d, 16); if (g >= d) inc += u; } \
    const int qex = inc - c; \
    const int q0row = rowbase + (int)ccum[r][cc_]; \
    const float* sdw = sdst2x + (q0row & (N - 1)) + qex; \
    const int ilo = q0row >> 13; \
    const float s_lo = ssrc[ilo]; \
    const float s_hi = ssrc[ilo + 1]; \
    const int krel = ((ilo + 1) << 13) - q0row - qex; \
    char* myreg = (PB) + r*512; \
    *(uint4*)(myreg + ((g*32)      ^ sw)) = make_uint4(0,0,0,0); \
    *(uint4*)(myreg + ((g*32 + 16) ^ sw)) = make_uint4(0,0,0,0); \
    float wv[16]; \
    _Pragma("unroll") \
    for (int k = 0; k < 16; ++k) wv[k] = sdw[k]; \
    unsigned mc = m; \
    _Pragma("unroll") \
    for (int k = 0; k < 16; ++k){ \
      const float ss = (k >= krel) ? s_hi : s_lo; \
      float e = ss + wv[k] + ab; \
      e = (e > 0.f) ? e : LEAKY * e; \
      const float p = __expf(e); \
      const int pos = __ffs(mc) - 1; \
      if (k < c){ \
        dsum += p; \
        *(unsigned short*)(myreg + ((g*32 + pos*2) ^ sw)) = f2bf(p); \
      } \
      mc &= mc - 1; \
    } \
  }

#define MM(PB, BR) { \
    const char* aP = (PB) + fr*512; \
    _Pragma("unroll") \
    for (int kk = 0; kk < 8; ++kk){ \
      bf16x8 av = *(const bf16x8*)(aP + ((kk*64 + ks*16) ^ sA)); \
      acc = __builtin_amdgcn_mfma_f32_16x16x32_bf16(av, BR[kk], acc, 0, 0, 0); \
    } \
  }

  PREFETCH(ch0, bregA)
  PRODUCE(0, buf0)
  __syncthreads();
  for (int cc = 0; cc < HALFCH; cc += 2){
    PREFETCH(ch0 + cc + 1, bregB)
    PRODUCE(cc + 1, buf1)
    MM(buf0, bregA)
    __syncthreads();
    if (cc + 2 < HALFCH){
      PREFETCH(ch0 + cc + 2, bregA)
      PRODUCE(cc + 2, buf0)
    }
    MM(buf1, bregB)
    __syncthreads();
  }
#undef PREFETCH
#undef PRODUCE
#undef MM

  // epilogue: partial denominators (produce roles) + partial numerators (mfma roles)
  #pragma unroll
  for (int d = 8; d > 0; d >>= 1) dsum += __shfl_xor(dsum, d, 16);
  if (g == 0) pden[(size_t)half*N + i0 + r] = dsum;
  #pragma unroll
  for (int reg = 0; reg < 4; ++reg){
    const int il = ks*4 + reg;
    pnum[(size_t)half*N*F + (size_t)(i0 + il)*F + fB] = acc[reg];
  }
}

// k_comb: out = elu((n0+n1)/(d0+d1))
extern "C" __global__ void __launch_bounds__(256)
k_comb(const float* __restrict__ pnum, const float* __restrict__ pden,
       float* __restrict__ out){
  const int idx = blockIdx.x * 256 + threadIdx.x;   // 0 .. N*F-1
  const int i = idx >> 6;
  const float dn = pden[i] + pden[N + i];
  const float nm = pnum[idx] + pnum[(size_t)N*F + idx];
  float v = (dn > 0.f) ? nm / dn : 0.f;
  out[idx] = (v > 0.f) ? v : (__expf(v) - 1.f);
}

extern "C" void kernel_launch(void* const* d_in, const int* in_sizes, int n_in,
                              void* d_out, int out_size, void* d_ws, size_t ws_size,
                              hipStream_t stream){
  const float* x   = (const float*)d_in[0];
  const int*   adj = (const int*)d_in[1];
  const float* ww  = (const float*)d_in[2];
  const float* wb  = (const float*)d_in[3];
  const float* aw  = (const float*)d_in[4];
  const float* ab  = (const float*)d_in[5];
  float* out = (float*)d_out;

  char* ws = (char*)d_ws;
  float*          h      = (float*)(ws);                       // 2 MB
  unsigned short* ht     = (unsigned short*)(ws + (2u<<20));   // 1 MB
  float*          ssrc   = (float*)(ws + (3u<<20));            // 32 KB
  float*          sdst2x = (float*)(ws + (3u<<20) + 32*1024);  // 64 KB
  int*            rowtot = (int*)(ws + (3u<<20) + 96*1024);    // 32 KB
  int*            base   = (int*)(ws + (3u<<20) + 128*1024);   // 32 KB
  unsigned short* ccnt   = (unsigned short*)(ws + (3u<<20) + 160*1024); // 512 KB
  unsigned short* bm     = (unsigned short*)(ws + (4u<<20));   // 8 MB
  float*          pnum   = (float*)(ws + (12u<<20));           // 4 MB
  float*          pden   = (float*)(ws + (16u<<20));           // 64 KB

  k_pack<<<N,      256, 0, stream>>>(adj, bm, ccnt, rowtot);
  k_h   <<<N/4,    256, 0, stream>>>(x, ww, wb, aw, h, ssrc, sdst2x);
  k_tr  <<<N/64,   256, 0, stream>>>(h, ht);
  k_scan<<<1,     1024, 0, stream>>>(rowtot, base);
  k_main<<<2*(N/BI), 256, 0, stream>>>(bm, ccnt, base, ht, ssrc, sdst2x, ab, pnum, pden);
  k_comb<<<(N*F)/256, 256, 0, stream>>>(pnum, pden, out);
}